// Round 5
// baseline (144.881 us; speedup 1.0000x reference)
//
#include <hip/hip_runtime.h>
#include <hip/hip_bf16.h>
#include <hip/hip_fp8.h>
#include <math.h>

typedef float f32x4 __attribute__((ext_vector_type(4)));
typedef int   i32x4 __attribute__((ext_vector_type(4)));
typedef int   v8i   __attribute__((ext_vector_type(8)));

constexpr int Nn = 8192;   // B*S
constexpr int Dd = 256;    // feature dim (== bytes per fp8 row)
constexpr float LOG2E     = 1.4426950408889634f;
constexpr float SIM_SCALE = 20.0f * LOG2E;   // (1/tau)*log2(e), tau=0.05
constexpr float SIM_BIAS  = -20.0f * LOG2E;  // fixed max = 1/tau (|q.k|<=1)
constexpr int   SCALE1    = 0x7F7F7F7F;      // E8M0 127 = 2^0 in every byte

// async global->LDS DMA, 16B/lane; LDS dst = wave-uniform base + lane*16.
typedef __attribute__((address_space(1))) const unsigned int gu32;
typedef __attribute__((address_space(3))) unsigned int lu32;
__device__ __forceinline__ void gload16(const unsigned char* g, unsigned char* l) {
  __builtin_amdgcn_global_load_lds((gu32*)(uintptr_t)g, (lu32*)(uintptr_t)l, 16, 0, 0);
}

// ---------------------------------------------------------------------------
// Kernel 1: L2-normalize rows -> fp8 e4m3; init cbias (SIM_BIAS pre-folded) /
// g_all / g_pos.  (Correctness-verified, unchanged.)
// ---------------------------------------------------------------------------
__global__ __launch_bounds__(256) void prep_kernel(const float* __restrict__ logits,
                                                   const float* __restrict__ labels,
                                                   const int* __restrict__ pad,
                                                   unsigned char* __restrict__ qb,
                                                   unsigned char* __restrict__ kb,
                                                   float* __restrict__ cbias,
                                                   float* __restrict__ g_all,
                                                   float* __restrict__ g_pos) {
  const int j = blockIdx.x * 256 + threadIdx.x;
  if (j < Nn) {
    cbias[j] = pad[j] ? SIM_BIAS : -1e30f;   // SIM_BIAS folded in (col term)
    g_all[j] = 0.0f;
    g_pos[j] = 0.0f;
  }

  const int gw   = (blockIdx.x * 256 + threadIdx.x) >> 6;
  const int lane = threadIdx.x & 63;
  const float* src;
  unsigned char* dst;
  int row;
  if (gw < Nn) { src = logits; dst = qb; row = gw; }
  else         { src = labels; dst = kb; row = gw - Nn; }

  const float4 v = *reinterpret_cast<const float4*>(src + (size_t)row * Dd + lane * 4);
  float ss = v.x * v.x + v.y * v.y + v.z * v.z + v.w * v.w;
#pragma unroll
  for (int m = 32; m >= 1; m >>= 1) ss += __shfl_xor(ss, m);
  const float scale = 1.0f / fmaxf(sqrtf(ss), 1e-12f);

  const __hip_fp8_e4m3 e0(v.x * scale);
  const __hip_fp8_e4m3 e1(v.y * scale);
  const __hip_fp8_e4m3 e2(v.z * scale);
  const __hip_fp8_e4m3 e3(v.w * scale);
  const unsigned int packed = (unsigned int)e0.__x |
                              ((unsigned int)e1.__x << 8) |
                              ((unsigned int)e2.__x << 16) |
                              ((unsigned int)e3.__x << 24);
  reinterpret_cast<unsigned int*>(dst + (size_t)row * Dd)[lane] = packed;
}

// ---------------------------------------------------------------------------
// Kernel 2 (R18): occupancy restructure.  Phase = 64 cols x FULL K (16KB B
// stage, both K-halves resident), wave tile 64x32 per phase:
//   - c[4][2] (32 regs, phase-local) instead of c[4][4] (64, loop-carried)
//     -> est ~170 live regs -> __launch_bounds__(256,3): 3 waves/SIMD
//   - LDS 48KB (A transit 32KB overlaid by B buf1 after the hoist)
//     -> 3 blocks/CU (was 2).  TLP: epilogue of one block overlaps MFMA of
//     two others instead of one.
//   - kk folded inside the phase: no accumulator zeroing, 1 barrier/phase,
//     10 barriers/block total.
// A staging + register hoist: byte-identical to the R13/R17-verified path.
// B LDS rows are 256B with the same 16B-group XOR involution
// (slot = g ^ (r&7)); the XOR touches only the low 3 group bits so the
// kk-half bit (group bit 3) is preserved -> (8+g)^sl == 8+(g^sl).
// Grid 64x16 (block = 128 rows x 512 cols, 8 phases).
// ---------------------------------------------------------------------------
__global__ __launch_bounds__(256, 3) void gemm_lse_kernel(const unsigned char* __restrict__ qb,
                                                          const unsigned char* __restrict__ kb,
                                                          const float* __restrict__ cbias,
                                                          const int* __restrict__ ad,
                                                          float* __restrict__ g_all,
                                                          float* __restrict__ g_pos) {
  __shared__ unsigned char smem[49152];
  // prologue: A.k0 [0,16K), A.k1 [16K,32K), B(ph0) [32K,48K)
  // main loop: B ping-pong buf0=[32K,48K) (even ph), buf1=[0,16K) (odd ph)

  const int tid  = threadIdx.x;
  const int lane = tid & 63;
  const int w    = tid >> 6;        // 0..3
  const int wrow  = (w >> 1) * 64;  // 0 or 64
  const int wcolL = (w & 1) * 32;   // 0 or 32 within the 64-col phase
  const int lq   = lane & 15;
  const int qd   = lane >> 4;
  const int rowBase = blockIdx.x * 128;
  const int colBase = blockIdx.y * 512;   // 8 phases of 64 cols

  // ---- A staging (verified R13 pattern, 128B rows) ----
  const int srl = lane >> 3;
  const int cg  = (lane & 7) ^ srl;
  const unsigned char* gA0 = qb + (size_t)(rowBase + w * 32 + srl) * Dd + cg * 16;
#pragma unroll
  for (int kk = 0; kk < 2; ++kk)
#pragma unroll
    for (int i = 0; i < 4; ++i)
      gload16(gA0 + (size_t)i * 8 * Dd + kk * 128,
              &smem[kk * 16384 + (w * 32 + i * 8) * 128]);

  // ---- B staging pointers (256B rows, 16-group swizzle) ----
  // wave stages rows [w*16, w*16+16); iter i covers 4 rows (1KB).
  // lane l -> row w*16 + i*4 + (l>>4), slot l&15 holds group (l&15)^(r&7),
  // r&7 = (i&1)*4 + (l>>4)  (no carry: l>>4 <= 3).
  const int rl = lane >> 4;   // 0..3
  const int sg = lane & 15;
  const unsigned char* gBe = kb + (size_t)(colBase + w * 16 + rl) * Dd + ((sg ^ rl) << 4);
  const unsigned char* gBo = kb + (size_t)(colBase + w * 16 + rl) * Dd + ((sg ^ (4 + rl)) << 4);

  {  // stage B(ph=0) -> buf0
    unsigned char* dB = &smem[32768 + (w * 16) * 256];
#pragma unroll
    for (int i = 0; i < 4; ++i)
      gload16((i & 1 ? gBo : gBe) + (size_t)i * 1024, dB + i * 1024);
  }

  // per-thread row metadata (16 rows: mt x r)
  int rowAd[4][4];
#pragma unroll
  for (int mt = 0; mt < 4; ++mt)
#pragma unroll
    for (int r = 0; r < 4; ++r)
      rowAd[mt][r] = ad[rowBase + wrow + mt * 16 + qd * 4 + r];

  float apA[4][4], apP[4][4];
#pragma unroll
  for (int mt = 0; mt < 4; ++mt)
#pragma unroll
    for (int r = 0; r < 4; ++r) {
      apA[mt][r] = 0.f;
      apP[mt][r] = 0.f;
    }

  __syncthreads();  // drains prologue DMA (A both halves + B(ph0))

  // ---- one-time A fragment hoist (A LDS region dead afterwards) ----
  const int sl = lq & 7;                  // == r&7 for every fragment row
  const int s0 = ((qd * 2) ^ sl) << 4;    // group g and g+1 slots (g = qd*2)
  const int s1 = ((qd * 2 + 1) ^ sl) << 4;

  v8i afReg[2][4];
#pragma unroll
  for (int kk = 0; kk < 2; ++kk) {
    const unsigned char* Ah = &smem[kk * 16384];
#pragma unroll
    for (int mt = 0; mt < 4; ++mt) {
      const int rb = (wrow + mt * 16 + lq) * 128;
      i32x4* ph_ = reinterpret_cast<i32x4*>(&afReg[kk][mt]);
      ph_[0] = *reinterpret_cast<const i32x4*>(&Ah[rb + s0]);
      ph_[1] = *reinterpret_cast<const i32x4*>(&Ah[rb + s1]);
    }
  }

  __syncthreads();  // hoist complete: buf1 region ([0,16K)) is now free

  const f32x4 CZ = (f32x4){0.f, 0.f, 0.f, 0.f};

  for (int ph = 0; ph < 8; ++ph) {
    if (ph < 7) {  // stage B(ph+1) into the other buffer
      unsigned char* dB = &smem[(((ph + 1) & 1) ? 0u : 32768u) + (w * 16) * 256];
      const size_t gOff = (size_t)(ph + 1) * 16384;  // 64 cols x 256B
#pragma unroll
      for (int i = 0; i < 4; ++i)
        gload16((i & 1 ? gBo : gBe) + gOff + (size_t)i * 1024, dB + i * 1024);
    }

    float colB[2];
    int colAd[2];
#pragma unroll
    for (int nt = 0; nt < 2; ++nt) {
      const int col = colBase + ph * 64 + wcolL + nt * 16 + lq;
      colB[nt]  = cbias[col];   // SIM_BIAS already folded in prep
      colAd[nt] = ad[col];
    }

    const unsigned char* Bh = &smem[(ph & 1) ? 0u : 32768u];
    f32x4 c[4][2];
#pragma unroll
    for (int nt = 0; nt < 2; ++nt) {
      const int rb = (wcolL + nt * 16 + lq) * 256;
      v8i bf0, bf1;
      i32x4* p0 = reinterpret_cast<i32x4*>(&bf0);
      p0[0] = *reinterpret_cast<const i32x4*>(&Bh[rb + s0]);          // kk0 g
      p0[1] = *reinterpret_cast<const i32x4*>(&Bh[rb + s1]);          // kk0 g+1
      i32x4* p1 = reinterpret_cast<i32x4*>(&bf1);
      p1[0] = *reinterpret_cast<const i32x4*>(&Bh[rb + s0 + 128]);    // kk1 g
      p1[1] = *reinterpret_cast<const i32x4*>(&Bh[rb + s1 + 128]);    // kk1 g+1
#pragma unroll
      for (int mt = 0; mt < 4; ++mt) {
        const f32x4 t = __builtin_amdgcn_mfma_scale_f32_16x16x128_f8f6f4(
            afReg[0][mt], bf0, CZ, 0, 0, 0, SCALE1, 0, SCALE1);
        c[mt][nt] = __builtin_amdgcn_mfma_scale_f32_16x16x128_f8f6f4(
            afReg[1][mt], bf1, t, 0, 0, 0, SCALE1, 0, SCALE1);
      }
    }

    // ---- epilogue for this phase (64 cols): exp2-accumulate to registers ----
#pragma unroll
    for (int mt = 0; mt < 4; ++mt) {
#pragma unroll
      for (int r = 0; r < 4; ++r) {
        float a = 0.f, p = 0.f;
#pragma unroll
        for (int nt = 0; nt < 2; ++nt) {
          const float e = __builtin_amdgcn_exp2f(fmaf(c[mt][nt][r], SIM_SCALE, colB[nt]));
          a += e;
          p += (colAd[nt] == rowAd[mt][r]) ? e : 0.f;
        }
        apA[mt][r] += a;
        apP[mt][r] += p;
      }
    }

    __syncthreads();  // drains B(ph+1) DMA; orders buffer reuse
  }

  // ---- final reduction: shfl-tree over the 16 lq lanes, then one atomic ----
  // (waves w and w^1 cover the same rows with disjoint col halves -> 2
  //  atomics/row/block, at retire)
#pragma unroll
  for (int mt = 0; mt < 4; ++mt) {
#pragma unroll
    for (int r = 0; r < 4; ++r) {
      float a = apA[mt][r], p = apP[mt][r];
#pragma unroll
      for (int m = 1; m < 16; m <<= 1) {
        a += __shfl_xor(a, m);
        p += __shfl_xor(p, m);
      }
      if (lq == 0) {
        const int row = rowBase + wrow + mt * 16 + qd * 4 + r;
        atomicAdd(&g_all[row], a);
        atomicAdd(&g_pos[row], p);
      }
    }
  }
}

// ---------------------------------------------------------------------------
// Kernel 3: loss = mean over valid rows of log(g_all) - log(g_pos).
// ---------------------------------------------------------------------------
__global__ __launch_bounds__(1024) void reduce_kernel(const float* __restrict__ g_all,
                                                      const float* __restrict__ g_pos,
                                                      const int* __restrict__ pad,
                                                      float* __restrict__ out) {
  __shared__ float sS[16], sC[16];
  const int t = threadIdx.x;
  float s = 0.f, c = 0.f;
  const float4* ga4 = (const float4*)g_all;
  const float4* gp4 = (const float4*)g_pos;
  const int4*   pd4 = (const int4*)pad;
  for (int i = t; i < Nn / 4; i += 1024) {
    const float4 ga = ga4[i];
    const float4 gp = gp4[i];
    const int4   pd = pd4[i];
    if (pd.x) { s += __logf(ga.x) - __logf(gp.x); c += 1.f; }
    if (pd.y) { s += __logf(ga.y) - __logf(gp.y); c += 1.f; }
    if (pd.z) { s += __logf(ga.z) - __logf(gp.z); c += 1.f; }
    if (pd.w) { s += __logf(ga.w) - __logf(gp.w); c += 1.f; }
  }
#pragma unroll
  for (int m = 32; m >= 1; m >>= 1) {
    s += __shfl_xor(s, m);
    c += __shfl_xor(c, m);
  }
  if ((t & 63) == 0) { sS[t >> 6] = s; sC[t >> 6] = c; }
  __syncthreads();
  if (t == 0) {
    float S = 0.f, C = 0.f;
#pragma unroll
    for (int i = 0; i < 16; ++i) { S += sS[i]; C += sC[i]; }
    out[0] = S / fmaxf(C, 1.0f);
  }
}

extern "C" void kernel_launch(void* const* d_in, const int* in_sizes, int n_in,
                              void* d_out, int out_size, void* d_ws, size_t ws_size,
                              hipStream_t stream) {
  const float* logits = (const float*)d_in[0];
  const float* labels = (const float*)d_in[1];
  const int*   pad    = (const int*)d_in[2];
  const int*   ad     = (const int*)d_in[3];

  char* ws = (char*)d_ws;
  unsigned char* qb = (unsigned char*)(ws);             // 2 MiB (fp8)
  unsigned char* kb = (unsigned char*)(ws + 2097152);   // 2 MiB (fp8)
  float*  cb   = (float*)(ws + 4194304);                // 32 KiB
  float*  gAll = (float*)(ws + 4227072);                // 32 KiB
  float*  gPos = (float*)(ws + 4259840);                // 32 KiB
  float*  out  = (float*)d_out;

  prep_kernel<<<4096, 256, 0, stream>>>(logits, labels, pad, qb, kb, cb, gAll, gPos);
  gemm_lse_kernel<<<dim3(64, 16), 256, 0, stream>>>(qb, kb, cb, ad, gAll, gPos);
  reduce_kernel<<<1, 1024, 0, stream>>>(gAll, gPos, pad, out);
}

// Round 6
// 100.130 us; speedup vs baseline: 1.4469x; 1.4469x over previous
//
#include <hip/hip_runtime.h>
#include <hip/hip_bf16.h>
#include <hip/hip_fp8.h>
#include <math.h>

typedef float f32x4 __attribute__((ext_vector_type(4)));
typedef int   i32x4 __attribute__((ext_vector_type(4)));
typedef int   v8i   __attribute__((ext_vector_type(8)));

constexpr int Nn = 8192;   // B*S
constexpr int Dd = 256;    // feature dim (== bytes per fp8 row)
constexpr float LOG2E     = 1.4426950408889634f;
constexpr float SIM_SCALE = 20.0f * LOG2E;   // (1/tau)*log2(e), tau=0.05
constexpr float SIM_BIAS  = -20.0f * LOG2E;  // fixed max = 1/tau (|q.k|<=1)
constexpr int   SCALE1    = 0x7F7F7F7F;      // E8M0 127 = 2^0 in every byte

// async global->LDS DMA, 16B/lane; LDS dst = wave-uniform base + lane*16.
typedef __attribute__((address_space(1))) const unsigned int gu32;
typedef __attribute__((address_space(3))) unsigned int lu32;
__device__ __forceinline__ void gload16(const unsigned char* g, unsigned char* l) {
  __builtin_amdgcn_global_load_lds((gu32*)(uintptr_t)g, (lu32*)(uintptr_t)l, 16, 0, 0);
}

#define VMCNT4() asm volatile("s_waitcnt vmcnt(4)" ::: "memory")
#define VMCNT0() asm volatile("s_waitcnt vmcnt(0)" ::: "memory")
#define LGKM0()  asm volatile("s_waitcnt lgkmcnt(0)" ::: "memory")
#define SCHEDB() __builtin_amdgcn_sched_barrier(0)
#define BAR()    __builtin_amdgcn_s_barrier()

// ---------------------------------------------------------------------------
// Kernel 1: L2-normalize rows -> fp8 e4m3; init cbias (SIM_BIAS pre-folded) /
// g_all / g_pos.  (Correctness-verified, unchanged.)
// ---------------------------------------------------------------------------
__global__ __launch_bounds__(256) void prep_kernel(const float* __restrict__ logits,
                                                   const float* __restrict__ labels,
                                                   const int* __restrict__ pad,
                                                   unsigned char* __restrict__ qb,
                                                   unsigned char* __restrict__ kb,
                                                   float* __restrict__ cbias,
                                                   float* __restrict__ g_all,
                                                   float* __restrict__ g_pos) {
  const int j = blockIdx.x * 256 + threadIdx.x;
  if (j < Nn) {
    cbias[j] = pad[j] ? SIM_BIAS : -1e30f;   // SIM_BIAS folded in (col term)
    g_all[j] = 0.0f;
    g_pos[j] = 0.0f;
  }

  const int gw   = (blockIdx.x * 256 + threadIdx.x) >> 6;
  const int lane = threadIdx.x & 63;
  const float* src;
  unsigned char* dst;
  int row;
  if (gw < Nn) { src = logits; dst = qb; row = gw; }
  else         { src = labels; dst = kb; row = gw - Nn; }

  const float4 v = *reinterpret_cast<const float4*>(src + (size_t)row * Dd + lane * 4);
  float ss = v.x * v.x + v.y * v.y + v.z * v.z + v.w * v.w;
#pragma unroll
  for (int m = 32; m >= 1; m >>= 1) ss += __shfl_xor(ss, m);
  const float scale = 1.0f / fmaxf(sqrtf(ss), 1e-12f);

  const __hip_fp8_e4m3 e0(v.x * scale);
  const __hip_fp8_e4m3 e1(v.y * scale);
  const __hip_fp8_e4m3 e2(v.z * scale);
  const __hip_fp8_e4m3 e3(v.w * scale);
  const unsigned int packed = (unsigned int)e0.__x |
                              ((unsigned int)e1.__x << 8) |
                              ((unsigned int)e2.__x << 16) |
                              ((unsigned int)e3.__x << 24);
  reinterpret_cast<unsigned int*>(dst + (size_t)row * Dd)[lane] = packed;
}

// ---------------------------------------------------------------------------
// Kernel 2 (R19): R17's verified compute (A-hoist, fragment math, epilogue,
// atomics-at-retire, (256,2) bounds) with the sync skeleton replaced by the
// T3/T4 counted-vmcnt pipeline:
//   - B tiles (16 x 16KB; tile t = col-tile t>>1, K-half t&1) in a 3-slot
//     ring overlaid on the dead A-transit LDS (48KB total).
//   - per iteration t: vmcnt(4) [waits tile t, issued 2 barriers ago; tile
//     t+1 stays in flight] -> raw s_barrier -> issue tile t+2 -> compute t.
//     vmcnt(0) only at t=15.  NO full drain in the main loop.
//   - stage issue AFTER the barrier => the slot it overwrites (tile t-1's,
//     ring distance 3) has no readers: all waves finished tile t-1's compute
//     before this barrier, and each compute phase ends with lgkmcnt(0) +
//     sched_barrier(0) so ds_reads cannot float past the barrier (rule #18).
//   - col metadata loads issued BEFORE the stage so in-order vmcnt
//     retirement doesn't stall on the fresh stage.
// ---------------------------------------------------------------------------
__global__ __launch_bounds__(256, 2) void gemm_lse_kernel(const unsigned char* __restrict__ qb,
                                                          const unsigned char* __restrict__ kb,
                                                          const float* __restrict__ cbias,
                                                          const int* __restrict__ ad,
                                                          float* __restrict__ g_all,
                                                          float* __restrict__ g_pos) {
  __shared__ unsigned char smem[49152];
  // prologue: A.k0 [0,16K), A.k1 [16K,32K), B slot0 [32K,48K)
  // loop: B ring slot0=[32K,48K) slot1=[0,16K) slot2=[16K,32K), tile t -> t%3

  const int tid  = threadIdx.x;
  const int lane = tid & 63;
  const int w    = tid >> 6;        // 0..3
  const int wrow  = (w >> 1) * 64;  // 0 or 64
  const int wcolL = (w & 1) * 64;   // 0 or 64 within the 128-col tile
  const int lq   = lane & 15;
  const int qd   = lane >> 4;
  const int rowBase = blockIdx.x * 128;
  const int colBase = blockIdx.y * 1024;   // 8 col-tiles of 128

  // staging constants (verified): wave w, iter i fills 8 LDS rows;
  // lane l -> row +(l>>3), logical 16B group (l&7)^(l>>3) (linear LDS dst).
  const int srl = lane >> 3;
  const int cg  = (lane & 7) ^ srl;
  const unsigned char* gA0 = qb + (size_t)(rowBase + w * 32 + srl) * Dd + cg * 16;
  const unsigned char* gB0 = kb + (size_t)(colBase + w * 32 + srl) * Dd + cg * 16;

  // ---- prologue: stage A (both K-halves) then B tile0 -> slot0 ----
#pragma unroll
  for (int kk = 0; kk < 2; ++kk)
#pragma unroll
    for (int i = 0; i < 4; ++i)
      gload16(gA0 + (size_t)i * 8 * Dd + kk * 128,
              &smem[kk * 16384 + (w * 32 + i * 8) * 128]);
#pragma unroll
  for (int i = 0; i < 4; ++i)
    gload16(gB0 + (size_t)i * 8 * Dd, &smem[32768 + (w * 32 + i * 8) * 128]);

  // per-thread row metadata (16 rows: mt x r)
  int rowAd[4][4];
#pragma unroll
  for (int mt = 0; mt < 4; ++mt)
#pragma unroll
    for (int r = 0; r < 4; ++r)
      rowAd[mt][r] = ad[rowBase + wrow + mt * 16 + qd * 4 + r];

  float apA[4][4], apP[4][4];
#pragma unroll
  for (int mt = 0; mt < 4; ++mt)
#pragma unroll
    for (int r = 0; r < 4; ++r) {
      apA[mt][r] = 0.f;
      apP[mt][r] = 0.f;
    }

  VMCNT4();   // A's 8 loads (oldest) complete; tile0's 4 may remain
  BAR();

  // ---- one-time A fragment hoist (A LDS region dead afterwards) ----
  const int sl = lq & 7;                  // == r&7 for every fragment row
  const int s0 = ((qd * 2) ^ sl) << 4;
  const int s1 = ((qd * 2 + 1) ^ sl) << 4;

  v8i afReg[2][4];
#pragma unroll
  for (int kk = 0; kk < 2; ++kk) {
    const unsigned char* Ah = &smem[kk * 16384];
#pragma unroll
    for (int mt = 0; mt < 4; ++mt) {
      const int rb = (wrow + mt * 16 + lq) * 128;
      i32x4* ph_ = reinterpret_cast<i32x4*>(&afReg[kk][mt]);
      ph_[0] = *reinterpret_cast<const i32x4*>(&Ah[rb + s0]);
      ph_[1] = *reinterpret_cast<const i32x4*>(&Ah[rb + s1]);
    }
  }

  __syncthreads();  // full drain (once): hoist reads done in ALL waves before
                    // slots 1/2 overwrite the A region; tile0 DMA also done.

  {  // issue tile1 -> slot1 [0,16K)
    unsigned char* dB = &smem[0 + (w * 32) * 128];
    const unsigned char* g = gB0 + 128;  // ct=0, kk=1
#pragma unroll
    for (int i = 0; i < 4; ++i)
      gload16(g + (size_t)i * 8 * Dd, dB + i * 8 * 128);
  }

  const f32x4 CZ = (f32x4){0.f, 0.f, 0.f, 0.f};
  f32x4 c[4][4];
  float colB[4];
  int colAd[4];

  for (int ct = 0; ct < 8; ++ct) {
    // slot bases for tiles 2ct, 2ct+1, 2ct+2, 2ct+3 (ring: tile t -> t%3)
    const int sA = (2 * ct) % 3;
    const unsigned bas0 = (sA == 0) ? 32768u : ((sA == 1) ? 0u : 16384u);
    const unsigned bas1 = (sA == 2) ? 32768u : ((sA == 0) ? 0u : 16384u);   // (2ct+1)%3
    const unsigned bas2 = (sA == 1) ? 32768u : ((sA == 2) ? 0u : 16384u);   // (2ct+2)%3
    const unsigned bas3 = bas0;                                             // (2ct+3)%3

    // ================= t = 2ct (kk=0): C-in = 0 =================
    {
      VMCNT4();   // tile 2ct (issued 2 barriers ago) complete; 2ct+1 in flight
      BAR();

      // col metadata first (so its vmcnt slot retires before the stage's)
#pragma unroll
      for (int nt = 0; nt < 4; ++nt) {
        const int col = colBase + ct * 128 + wcolL + nt * 16 + lq;
        colB[nt]  = cbias[col];   // SIM_BIAS already folded in prep
        colAd[nt] = ad[col];
      }

      if (ct < 7) {  // issue tile 2ct+2 -> bas2 (its old readers are done)
        unsigned char* dB = &smem[bas2 + (w * 32) * 128];
        const unsigned char* g = gB0 + (size_t)((ct + 1) * 128) * Dd;
#pragma unroll
        for (int i = 0; i < 4; ++i)
          gload16(g + (size_t)i * 8 * Dd, dB + i * 8 * 128);
      }

      const unsigned char* Bh = &smem[bas0];
#pragma unroll
      for (int nt = 0; nt < 4; ++nt) {
        const int rb = (wcolL + nt * 16 + lq) * 128;
        v8i bf;
        i32x4* pb = reinterpret_cast<i32x4*>(&bf);
        pb[0] = *reinterpret_cast<const i32x4*>(&Bh[rb + s0]);
        pb[1] = *reinterpret_cast<const i32x4*>(&Bh[rb + s1]);
#pragma unroll
        for (int mt = 0; mt < 4; ++mt)
          c[mt][nt] = __builtin_amdgcn_mfma_scale_f32_16x16x128_f8f6f4(
              afReg[0][mt], bf, CZ, 0, 0, 0, SCALE1, 0, SCALE1);
      }
      LGKM0();   // pin this phase's ds_reads inside the phase (rule #18)
      SCHEDB();
    }

    // ================= t = 2ct+1 (kk=1): accumulate + epilogue =================
    {
      if (ct < 7) { VMCNT4(); } else { VMCNT0(); }  // tile 2ct+1 complete
      BAR();

      if (ct < 7) {  // issue tile 2ct+3 -> bas3
        unsigned char* dB = &smem[bas3 + (w * 32) * 128];
        const unsigned char* g = gB0 + (size_t)((ct + 1) * 128) * Dd + 128;
#pragma unroll
        for (int i = 0; i < 4; ++i)
          gload16(g + (size_t)i * 8 * Dd, dB + i * 8 * 128);
      }

      const unsigned char* Bh = &smem[bas1];
#pragma unroll
      for (int nt = 0; nt < 4; ++nt) {
        const int rb = (wcolL + nt * 16 + lq) * 128;
        v8i bf;
        i32x4* pb = reinterpret_cast<i32x4*>(&bf);
        pb[0] = *reinterpret_cast<const i32x4*>(&Bh[rb + s0]);
        pb[1] = *reinterpret_cast<const i32x4*>(&Bh[rb + s1]);
#pragma unroll
        for (int mt = 0; mt < 4; ++mt)
          c[mt][nt] = __builtin_amdgcn_mfma_scale_f32_16x16x128_f8f6f4(
              afReg[1][mt], bf, c[mt][nt], 0, 0, 0, SCALE1, 0, SCALE1);
      }
      LGKM0();
      SCHEDB();

      // ---- epilogue for col-tile ct: exp2-accumulate into registers ----
#pragma unroll
      for (int mt = 0; mt < 4; ++mt) {
#pragma unroll
        for (int r = 0; r < 4; ++r) {
          float a = 0.f, p = 0.f;
#pragma unroll
          for (int nt = 0; nt < 4; ++nt) {
            const float e = __builtin_amdgcn_exp2f(fmaf(c[mt][nt][r], SIM_SCALE, colB[nt]));
            a += e;
            p += (colAd[nt] == rowAd[mt][r]) ? e : 0.f;
          }
          apA[mt][r] += a;
          apP[mt][r] += p;
        }
      }
    }
  }

  // ---- final reduction: shfl-tree over the 16 lq lanes, then one atomic ----
#pragma unroll
  for (int mt = 0; mt < 4; ++mt) {
#pragma unroll
    for (int r = 0; r < 4; ++r) {
      float a = apA[mt][r], p = apP[mt][r];
#pragma unroll
      for (int m = 1; m < 16; m <<= 1) {
        a += __shfl_xor(a, m);
        p += __shfl_xor(p, m);
      }
      if (lq == 0) {
        const int row = rowBase + wrow + mt * 16 + qd * 4 + r;
        atomicAdd(&g_all[row], a);
        atomicAdd(&g_pos[row], p);
      }
    }
  }
}

// ---------------------------------------------------------------------------
// Kernel 3: loss = mean over valid rows of log(g_all) - log(g_pos).
// ---------------------------------------------------------------------------
__global__ __launch_bounds__(1024) void reduce_kernel(const float* __restrict__ g_all,
                                                      const float* __restrict__ g_pos,
                                                      const int* __restrict__ pad,
                                                      float* __restrict__ out) {
  __shared__ float sS[16], sC[16];
  const int t = threadIdx.x;
  float s = 0.f, c = 0.f;
  const float4* ga4 = (const float4*)g_all;
  const float4* gp4 = (const float4*)g_pos;
  const int4*   pd4 = (const int4*)pad;
  for (int i = t; i < Nn / 4; i += 1024) {
    const float4 ga = ga4[i];
    const float4 gp = gp4[i];
    const int4   pd = pd4[i];
    if (pd.x) { s += __logf(ga.x) - __logf(gp.x); c += 1.f; }
    if (pd.y) { s += __logf(ga.y) - __logf(gp.y); c += 1.f; }
    if (pd.z) { s += __logf(ga.z) - __logf(gp.z); c += 1.f; }
    if (pd.w) { s += __logf(ga.w) - __logf(gp.w); c += 1.f; }
  }
#pragma unroll
  for (int m = 32; m >= 1; m >>= 1) {
    s += __shfl_xor(s, m);
    c += __shfl_xor(c, m);
  }
  if ((t & 63) == 0) { sS[t >> 6] = s; sC[t >> 6] = c; }
  __syncthreads();
  if (t == 0) {
    float S = 0.f, C = 0.f;
#pragma unroll
    for (int i = 0; i < 16; ++i) { S += sS[i]; C += sC[i]; }
    out[0] = S / fmaxf(C, 1.0f);
  }
}

extern "C" void kernel_launch(void* const* d_in, const int* in_sizes, int n_in,
                              void* d_out, int out_size, void* d_ws, size_t ws_size,
                              hipStream_t stream) {
  const float* logits = (const float*)d_in[0];
  const float* labels = (const float*)d_in[1];
  const int*   pad    = (const int*)d_in[2];
  const int*   ad     = (const int*)d_in[3];

  char* ws = (char*)d_ws;
  unsigned char* qb = (unsigned char*)(ws);             // 2 MiB (fp8)
  unsigned char* kb = (unsigned char*)(ws + 2097152);   // 2 MiB (fp8)
  float*  cb   = (float*)(ws + 4194304);                // 32 KiB
  float*  gAll = (float*)(ws + 4227072);                // 32 KiB
  float*  gPos = (float*)(ws + 4259840);                // 32 KiB
  float*  out  = (float*)d_out;

  prep_kernel<<<4096, 256, 0, stream>>>(logits, labels, pad, qb, kb, cb, gAll, gPos);
  gemm_lse_kernel<<<dim3(64, 8), 256, 0, stream>>>(qb, kb, cb, ad, gAll, gPos);
  reduce_kernel<<<1, 1024, 0, stream>>>(gAll, gPos, pad, out);
}